// Round 1
// 587.567 us; speedup vs baseline: 1.1497x; 1.1497x over previous
//
#include <hip/hip_runtime.h>
#include <hip/hip_bf16.h>

// Problem constants
#define OUT_F 11008   // N
#define IN_F  4096    // K
#define M_DIM 4096    // 4 * 1024

typedef __attribute__((ext_vector_type(8))) short bf16x8;          // MFMA A/B frag
typedef __attribute__((ext_vector_type(4))) float f32x4;           // MFMA C/D frag
typedef __attribute__((ext_vector_type(8))) unsigned short us8;    // 16B of bf16 bits

// ---------------------------------------------------------------------------
// Kernel 1: x fp32 -> bf16 (RNE), 8 elems/thread
// ---------------------------------------------------------------------------
__device__ __forceinline__ unsigned short f2bf_rne(float f) {
    unsigned u = __builtin_bit_cast(unsigned, f);
    u += 0x7fffu + ((u >> 16) & 1u);
    return (unsigned short)(u >> 16);
}

__global__ void cvt_x_kernel(const float* __restrict__ x,
                             unsigned short* __restrict__ xb) {
    size_t i = ((size_t)blockIdx.x * blockDim.x + threadIdx.x) * 8;
    float4 a = *(const float4*)(x + i);
    float4 b = *(const float4*)(x + i + 4);
    us8 o;
    o[0] = f2bf_rne(a.x); o[1] = f2bf_rne(a.y);
    o[2] = f2bf_rne(a.z); o[3] = f2bf_rne(a.w);
    o[4] = f2bf_rne(b.x); o[5] = f2bf_rne(b.y);
    o[6] = f2bf_rne(b.z); o[7] = f2bf_rne(b.w);
    *(us8*)(xb + i) = o;
}

// ---------------------------------------------------------------------------
// Kernel 2: unpack 2-bit weights -> bf16 [OUT_F][IN_F] (B^T layout).
// ---------------------------------------------------------------------------
__global__ void unpack_w_kernel(const int* __restrict__ pw,
                                unsigned short* __restrict__ wb) {
    size_t i = (size_t)blockIdx.x * blockDim.x + threadIdx.x;
    int4 v = ((const int4*)pw)[i];
    const unsigned long long LUT = 0x40003F800000BF80ull;
    us8 o0, o1;
#pragma unroll
    for (int j = 0; j < 4; j++) {
        o0[j]     = (unsigned short)(LUT >> (((v.x >> (2 * j)) & 3) * 16));
        o0[4 + j] = (unsigned short)(LUT >> (((v.y >> (2 * j)) & 3) * 16));
        o1[j]     = (unsigned short)(LUT >> (((v.z >> (2 * j)) & 3) * 16));
        o1[4 + j] = (unsigned short)(LUT >> (((v.w >> (2 * j)) & 3) * 16));
    }
    ((us8*)wb)[i * 2]     = o0;
    ((us8*)wb)[i * 2 + 1] = o1;
}

// ---------------------------------------------------------------------------
// Kernel 3: bf16 GEMM, 256x256 tile, BK=64, 8 waves (2x4), 8-phase schedule
// (T1 XCD swizzle + T2-equivalent XOR-slot LDS + T3/T4 counted vmcnt + T5
//  setprio), per the m201 template re-derived for this shape.
//
// LDS: lds[buf 2][mat A/B][khalf 2][row 256][4 slots x 8 bf16] = 128 KiB.
//  - slot for (row, seg) = seg ^ ((row>>1)&3); frag reads are 2-way = free.
//  - Staging (global_load_lds, linear dest = base + lane*16): lane l covers
//    row chunk*16 + l/4, slot l&3 => fetch global seg (l&3)^((l>>3)&3).
//
// Schedule proof (per-wave vmcnt units; 1 half-tile slot = 2 loads):
//  K-tile kt's 4 slots (A-k0,B-k0,A-k1,B-k1) are issued one per phase during
//  kt-1 (offset 4 => writes only buf^1 while buf is read; reads of buf^1's
//  old data finished at kt-1's entry barrier). Waits:
//   - end p1: outstanding <=8, wait vmcnt(4) => all but 2 newest slots landed
//     => current kt's A-k1,B-k1 landed before p2/p3 read them.
//   - end p3: wait vmcnt(4) => kt+1's A-k0,B-k0 landed before next p0 reads.
//  Steady state never drains to 0; last K-tile: p1 waits vmcnt(0) (epilogue
//  drain), p3 skips (nothing staged, nothing left to read).
// ---------------------------------------------------------------------------
#define LGKM0() do { asm volatile("s_waitcnt lgkmcnt(0)" ::: "memory"); \
                     __builtin_amdgcn_sched_barrier(0); } while (0)
#define VMCNT(n) do { asm volatile("s_waitcnt vmcnt(" #n ")" ::: "memory"); \
                      __builtin_amdgcn_sched_barrier(0); } while (0)

__global__ __launch_bounds__(512, 2) void gemm_kernel(
    const unsigned short* __restrict__ A,   // [M_DIM][IN_F] bf16 bits
    const unsigned short* __restrict__ B,   // [OUT_F][IN_F] bf16 bits
    float* __restrict__ C,                  // [M_DIM][OUT_F]
    const float* __restrict__ scale_ptr) {
    constexpr int K  = IN_F;
    constexpr int N  = OUT_F;
    constexpr int NT = K / 64;              // 64 K-tiles

    __shared__ unsigned short lds[2][2][2][256][32];   // 128 KiB

    const int tid  = threadIdx.x;
    const int wave = tid >> 6;
    const int lane = tid & 63;
    const int quad = lane >> 4;
    const int mrow = lane & 15;
    const int sw   = quad ^ ((mrow >> 1) & 3);          // frag-read slot

    // staging lane decomposition
    const int srow = lane >> 2;                         // 0..15 (row in chunk)
    const int sseg = (lane & 3) ^ ((lane >> 3) & 3);    // source k-seg

    // Block swizzle: XCD x owns 86 consecutive tiles = 2 bm-rows x 43 bn.
    // A-panels (2x2MB) stay L2-resident per XCD; all XCDs walk bn in step so
    // B (90MB < L3) is HBM-fetched ~once. 688 % 8 == 0 => bijective.
    const int lin = blockIdx.x;             // 0..687
    const int xcd = lin & 7;
    const int q   = lin >> 3;               // 0..85
    const int bm  = xcd * 2 + q / 43;       // 0..15
    const int bn  = q % 43;                 // 0..42

    const int wm = (wave >> 2) * 128;       // wave M offset in tile
    const int wn = (wave & 3) * 64;         // wave N offset in tile

    const unsigned short* Ag = A + (size_t)bm * 256 * K;
    const unsigned short* Bg = B + (size_t)bn * 256 * K;

    f32x4 acc[8][4];
#pragma unroll
    for (int i = 0; i < 8; i++)
#pragma unroll
        for (int j = 0; j < 4; j++) acc[i][j] = (f32x4){0.f, 0.f, 0.f, 0.f};

    // Stage one half-tile (mat, khalf) of K-tile starting at k-elem kbase
    // into buffer nb. 2 x global_load_lds per wave (16 rows each).
    auto STAGE = [&](int mat, int nb, int h, int kbase) {
#pragma unroll
        for (int c = 0; c < 2; ++c) {
            const int chunk = wave * 2 + c;
            const int grow  = chunk * 16 + srow;
            const unsigned short* src =
                (mat ? Bg : Ag) + (size_t)grow * K + kbase + sseg * 8;
            __builtin_amdgcn_global_load_lds(
                (const __attribute__((address_space(1))) void*)src,
                (__attribute__((address_space(3))) void*)
                    (&lds[nb][mat][h][0][0] + chunk * 512),
                16, 0, 0);
        }
    };

    // Prologue: stage K-tile 0 fully; guarantee its k0 slots before p0 reads.
    STAGE(0, 0, 0, 0);    // A-k0
    STAGE(1, 0, 0, 0);    // B-k0
    STAGE(0, 0, 1, 32);   // A-k1
    STAGE(1, 0, 1, 32);   // B-k1
    VMCNT(4);             // oldest 4 loads (A-k0,B-k0) landed
    __builtin_amdgcn_s_barrier();

    bf16x8 a[8], b0, b1, b2, b3;

#pragma unroll 2
    for (int kt = 0; kt < NT; ++kt) {
        const int  buf  = kt & 1;
        const int  nbuf = buf ^ 1;
        const bool pf   = (kt + 1 < NT);
        const int  kn   = (kt + 1) * 64;   // next K-tile k base

        // ---- phase 0: k-half 0, n-frags 0,1  (reads A-k0, B-k0)
#pragma unroll
        for (int t = 0; t < 8; ++t)
            a[t] = *(const bf16x8*)&lds[buf][0][0][wm + t * 16 + mrow][sw * 8];
        b0 = *(const bf16x8*)&lds[buf][1][0][wn +  0 + mrow][sw * 8];
        b1 = *(const bf16x8*)&lds[buf][1][0][wn + 16 + mrow][sw * 8];
        if (pf) STAGE(0, nbuf, 0, kn);
        __builtin_amdgcn_s_barrier();
        LGKM0();
        __builtin_amdgcn_s_setprio(1);
#pragma unroll
        for (int t = 0; t < 8; ++t) {
            acc[t][0] = __builtin_amdgcn_mfma_f32_16x16x32_bf16(a[t], b0, acc[t][0], 0, 0, 0);
            acc[t][1] = __builtin_amdgcn_mfma_f32_16x16x32_bf16(a[t], b1, acc[t][1], 0, 0, 0);
        }
        __builtin_amdgcn_s_setprio(0);
        __builtin_amdgcn_s_barrier();

        // ---- phase 1: k-half 0, n-frags 2,3  (reads B-k0)
        b2 = *(const bf16x8*)&lds[buf][1][0][wn + 32 + mrow][sw * 8];
        b3 = *(const bf16x8*)&lds[buf][1][0][wn + 48 + mrow][sw * 8];
        if (pf) STAGE(1, nbuf, 0, kn);
        __builtin_amdgcn_s_barrier();
        LGKM0();
        __builtin_amdgcn_s_setprio(1);
#pragma unroll
        for (int t = 0; t < 8; ++t) {
            acc[t][2] = __builtin_amdgcn_mfma_f32_16x16x32_bf16(a[t], b2, acc[t][2], 0, 0, 0);
            acc[t][3] = __builtin_amdgcn_mfma_f32_16x16x32_bf16(a[t], b3, acc[t][3], 0, 0, 0);
        }
        __builtin_amdgcn_s_setprio(0);
        if (pf) { VMCNT(4); } else { VMCNT(0); }  // guarantee this kt's k1 slots
        __builtin_amdgcn_s_barrier();

        // ---- phase 2: k-half 1, n-frags 0,1  (reads A-k1, B-k1)
#pragma unroll
        for (int t = 0; t < 8; ++t)
            a[t] = *(const bf16x8*)&lds[buf][0][1][wm + t * 16 + mrow][sw * 8];
        b0 = *(const bf16x8*)&lds[buf][1][1][wn +  0 + mrow][sw * 8];
        b1 = *(const bf16x8*)&lds[buf][1][1][wn + 16 + mrow][sw * 8];
        if (pf) STAGE(0, nbuf, 1, kn + 32);
        __builtin_amdgcn_s_barrier();
        LGKM0();
        __builtin_amdgcn_s_setprio(1);
#pragma unroll
        for (int t = 0; t < 8; ++t) {
            acc[t][0] = __builtin_amdgcn_mfma_f32_16x16x32_bf16(a[t], b0, acc[t][0], 0, 0, 0);
            acc[t][1] = __builtin_amdgcn_mfma_f32_16x16x32_bf16(a[t], b1, acc[t][1], 0, 0, 0);
        }
        __builtin_amdgcn_s_setprio(0);
        __builtin_amdgcn_s_barrier();

        // ---- phase 3: k-half 1, n-frags 2,3  (reads B-k1)
        b2 = *(const bf16x8*)&lds[buf][1][1][wn + 32 + mrow][sw * 8];
        b3 = *(const bf16x8*)&lds[buf][1][1][wn + 48 + mrow][sw * 8];
        if (pf) STAGE(1, nbuf, 1, kn + 32);
        __builtin_amdgcn_s_barrier();
        LGKM0();
        __builtin_amdgcn_s_setprio(1);
#pragma unroll
        for (int t = 0; t < 8; ++t) {
            acc[t][2] = __builtin_amdgcn_mfma_f32_16x16x32_bf16(a[t], b2, acc[t][2], 0, 0, 0);
            acc[t][3] = __builtin_amdgcn_mfma_f32_16x16x32_bf16(a[t], b3, acc[t][3], 0, 0, 0);
        }
        __builtin_amdgcn_s_setprio(0);
        if (pf) { VMCNT(4); }  // guarantee next kt's k0 slots before its p0
        __builtin_amdgcn_s_barrier();
    }

    // Epilogue: C/D layout col=lane&15, row=quad*4+reg (same as verified 128²)
    const float scale = *scale_ptr;
    float* Cg = C + (size_t)(bm * 256 + wm) * N + bn * 256 + wn;
#pragma unroll
    for (int i = 0; i < 8; ++i) {
#pragma unroll
        for (int j = 0; j < 4; ++j) {
#pragma unroll
            for (int r = 0; r < 4; ++r) {
                const int row = i * 16 + quad * 4 + r;
                const int col = j * 16 + mrow;
                Cg[(size_t)row * N + col] = acc[i][j][r] * scale;
            }
        }
    }
}

// ---------------------------------------------------------------------------
// Launch
// ---------------------------------------------------------------------------
extern "C" void kernel_launch(void* const* d_in, const int* in_sizes, int n_in,
                              void* d_out, int out_size, void* d_ws, size_t ws_size,
                              hipStream_t stream) {
    const float* x   = (const float*)d_in[0];     // [4,1024,4096] fp32
    const int* pw    = (const int*)d_in[1];       // [11008*4096/4] int32
    const float* wsc = (const float*)d_in[2];     // [1] fp32

    float* out = (float*)d_out;                   // [4,1024,11008] fp32

    unsigned short* xb = (unsigned short*)d_ws;
    unsigned short* wb = (unsigned short*)((char*)d_ws + (size_t)M_DIM * IN_F * 2);

    // x convert: 16,777,216 elems / 8 per thread
    cvt_x_kernel<<<8192, 256, 0, stream>>>(x, xb);

    // unpack: 11,272,192 packed ints / 4 per thread
    unpack_w_kernel<<<11008, 256, 0, stream>>>(pw, wb);

    // GEMM: 688 tiles = 16 (M/256) x 43 (N/256), 512 threads (8 waves)
    gemm_kernel<<<688, 512, 0, stream>>>(xb, wb, out, wsc);
}

// Round 2
// 584.201 us; speedup vs baseline: 1.1563x; 1.0058x over previous
//
#include <hip/hip_runtime.h>
#include <hip/hip_bf16.h>

// Problem constants
#define OUT_F 11008   // N
#define IN_F  4096    // K
#define M_DIM 4096    // 4 * 1024

typedef __attribute__((ext_vector_type(8))) short bf16x8;          // MFMA A/B frag
typedef __attribute__((ext_vector_type(4))) float f32x4;           // MFMA C/D frag
typedef __attribute__((ext_vector_type(8))) unsigned short us8;    // 16B of bf16 bits

// ---------------------------------------------------------------------------
// Kernel 1: x fp32 -> bf16 (RNE), 8 elems/thread
// ---------------------------------------------------------------------------
__device__ __forceinline__ unsigned short f2bf_rne(float f) {
    unsigned u = __builtin_bit_cast(unsigned, f);
    u += 0x7fffu + ((u >> 16) & 1u);
    return (unsigned short)(u >> 16);
}

__global__ void cvt_x_kernel(const float* __restrict__ x,
                             unsigned short* __restrict__ xb) {
    size_t i = ((size_t)blockIdx.x * blockDim.x + threadIdx.x) * 8;
    float4 a = *(const float4*)(x + i);
    float4 b = *(const float4*)(x + i + 4);
    us8 o;
    o[0] = f2bf_rne(a.x); o[1] = f2bf_rne(a.y);
    o[2] = f2bf_rne(a.z); o[3] = f2bf_rne(a.w);
    o[4] = f2bf_rne(b.x); o[5] = f2bf_rne(b.y);
    o[6] = f2bf_rne(b.z); o[7] = f2bf_rne(b.w);
    *(us8*)(xb + i) = o;
}

// ---------------------------------------------------------------------------
// Kernel 2: unpack 2-bit weights -> bf16 [OUT_F][IN_F] (B^T layout).
// ---------------------------------------------------------------------------
__global__ void unpack_w_kernel(const int* __restrict__ pw,
                                unsigned short* __restrict__ wb) {
    size_t i = (size_t)blockIdx.x * blockDim.x + threadIdx.x;
    int4 v = ((const int4*)pw)[i];
    const unsigned long long LUT = 0x40003F800000BF80ull;
    us8 o0, o1;
#pragma unroll
    for (int j = 0; j < 4; j++) {
        o0[j]     = (unsigned short)(LUT >> (((v.x >> (2 * j)) & 3) * 16));
        o0[4 + j] = (unsigned short)(LUT >> (((v.y >> (2 * j)) & 3) * 16));
        o1[j]     = (unsigned short)(LUT >> (((v.z >> (2 * j)) & 3) * 16));
        o1[4 + j] = (unsigned short)(LUT >> (((v.w >> (2 * j)) & 3) * 16));
    }
    ((us8*)wb)[i * 2]     = o0;
    ((us8*)wb)[i * 2 + 1] = o1;
}

// ---------------------------------------------------------------------------
// Kernel 3: bf16 GEMM, 256x256 tile, BK=64, 8 waves (2x4), 4-phase/K-tile
// schedule with DEEP prefetch (5-phase issue->wait distance, > HBM latency).
//
// LDS: lds[buf 2][mat A/B][khalf 2][row 256][4 slots x 8 bf16] = 128 KiB.
//  - slot for (row, seg) = seg ^ ((row>>1)&3); frag reads are 2-way = free.
//  - Staging (global_load_lds, linear dest = base + lane*16): lane l covers
//    row chunk*16 + l/4, slot l&3 => fetch global seg (l&3)^((l>>3)&3).
//
// Slot = (mat, khalf) quarter of a K-tile: s0=A-k0, s1=B-k0, s2=A-k1, s3=B-k1.
// Region last-read phases within tile kt: s0 @p0, s1 @p1, s2 @p2, s3 @p3.
// Therefore stage-earliest (one barrier after last read) gives the steady
// issue schedule (1 stage = 2 global_load_lds per wave, per phase):
//   kt.p0: s3(kt+1) -> nbuf   (region held kt-1's B-k1, last read kt-1.p3)
//   kt.p1: s0(kt+2) -> buf    (region holds kt's A-k0, last read kt.p0)
//   kt.p2: s1(kt+2) -> buf    (kt's B-k0, last read kt.p1)
//   kt.p3: s2(kt+2) -> buf    (kt's A-k1, last read kt.p2)
// Event order: ... s2(kt)@kt-2.p3, s3(kt)@kt-1.p0, s0(kt+1)@kt-1.p1,
//   s1(kt+1)@kt-1.p2, s2(kt+1)@kt-1.p3, s3(kt+1)@kt.p0, s0(kt+2)@kt.p1,
//   [W1 end kt.p1], s1(kt+2)@kt.p2, s2(kt+2)@kt.p3, [W2 end kt.p3], ...
// W1 needs s3(kt) done (covers s2) before p2/p3 reads: 5 newer stages in
//   flight = vmcnt(10).  Issue->wait = 5 phases.
// W2 needs s1(kt+1) done (covers s0) before kt+1.p0 reads: 5 newer stages
//   = vmcnt(10).  Issue->wait = 5 phases.
// Tail (kt >= NT-2): stage guards fail; drain with vmcnt(0) (2/64 tiles).
// Waits sit BEFORE the exit barrier; dependent ds_reads are after it, so
// per-wave vmcnt + barrier => all waves' loads landed (cross-wave safe).
// ---------------------------------------------------------------------------
#define LGKM0() do { asm volatile("s_waitcnt lgkmcnt(0)" ::: "memory"); \
                     __builtin_amdgcn_sched_barrier(0); } while (0)
#define VMCNT(n) do { asm volatile("s_waitcnt vmcnt(" #n ")" ::: "memory"); \
                      __builtin_amdgcn_sched_barrier(0); } while (0)

__global__ __launch_bounds__(512, 2) void gemm_kernel(
    const unsigned short* __restrict__ A,   // [M_DIM][IN_F] bf16 bits
    const unsigned short* __restrict__ B,   // [OUT_F][IN_F] bf16 bits
    float* __restrict__ C,                  // [M_DIM][OUT_F]
    const float* __restrict__ scale_ptr) {
    constexpr int K  = IN_F;
    constexpr int N  = OUT_F;
    constexpr int NT = K / 64;              // 64 K-tiles

    __shared__ unsigned short lds[2][2][2][256][32];   // 128 KiB

    const int tid  = threadIdx.x;
    const int wave = tid >> 6;
    const int lane = tid & 63;
    const int quad = lane >> 4;
    const int mrow = lane & 15;
    const int sw   = quad ^ ((mrow >> 1) & 3);          // frag-read slot

    // staging lane decomposition
    const int srow = lane >> 2;                         // 0..15 (row in chunk)
    const int sseg = (lane & 3) ^ ((lane >> 3) & 3);    // source k-seg

    // Block swizzle: XCD x owns 86 consecutive tiles = 2 bm-rows x 43 bn.
    // A-panels (2x2MB) stay L2-resident per XCD; all XCDs walk bn in step so
    // B (90MB < L3) is HBM-fetched ~once. 688 % 8 == 0 => bijective.
    const int lin = blockIdx.x;             // 0..687
    const int xcd = lin & 7;
    const int q   = lin >> 3;               // 0..85
    const int bm  = xcd * 2 + q / 43;       // 0..15
    const int bn  = q % 43;                 // 0..42

    const int wm = (wave >> 2) * 128;       // wave M offset in tile
    const int wn = (wave & 3) * 64;         // wave N offset in tile

    const unsigned short* Ag = A + (size_t)bm * 256 * K;
    const unsigned short* Bg = B + (size_t)bn * 256 * K;

    f32x4 acc[8][4];
#pragma unroll
    for (int i = 0; i < 8; i++)
#pragma unroll
        for (int j = 0; j < 4; j++) acc[i][j] = (f32x4){0.f, 0.f, 0.f, 0.f};

    // Stage one half-tile slot (mat, khalf) of the K-tile at k-elem kbase
    // into buffer nb. 2 x global_load_lds (16B) per wave.
    auto STAGE = [&](int mat, int nb, int h, int kbase) {
#pragma unroll
        for (int c = 0; c < 2; ++c) {
            const int chunk = wave * 2 + c;
            const int grow  = chunk * 16 + srow;
            const unsigned short* src =
                (mat ? Bg : Ag) + (size_t)grow * K + kbase + sseg * 8;
            __builtin_amdgcn_global_load_lds(
                (const __attribute__((address_space(1))) void*)src,
                (__attribute__((address_space(3))) void*)
                    (&lds[nb][mat][h][0][0] + chunk * 512),
                16, 0, 0);
        }
    };

    // Prologue: issue 7 slots in steady-state order (s0..s3 of tile 0,
    // s0..s2 of tile 1), then wait all-but-10 => s0,s1 of tile 0 landed.
    STAGE(0, 0, 0, 0);     // s0(0)
    STAGE(1, 0, 0, 0);     // s1(0)
    STAGE(0, 0, 1, 32);    // s2(0)
    STAGE(1, 0, 1, 32);    // s3(0)
    STAGE(0, 1, 0, 64);    // s0(1)
    STAGE(1, 1, 0, 64);    // s1(1)
    STAGE(0, 1, 1, 96);    // s2(1)
    VMCNT(10);
    __builtin_amdgcn_s_barrier();

    bf16x8 a[8], b0, b1, b2, b3;

#pragma unroll 2
    for (int kt = 0; kt < NT; ++kt) {
        const int  buf  = kt & 1;
        const int  nbuf = buf ^ 1;
        const bool pf1  = (kt + 1 < NT);
        const bool pf2  = (kt + 2 < NT);
        const int  kn1  = (kt + 1) * 64;
        const int  kn2  = (kt + 2) * 64;

        // ---- phase 0: k-half 0, n-frags 0,1  (reads A-k0, B-k0 of kt)
#pragma unroll
        for (int t = 0; t < 8; ++t)
            a[t] = *(const bf16x8*)&lds[buf][0][0][wm + t * 16 + mrow][sw * 8];
        b0 = *(const bf16x8*)&lds[buf][1][0][wn +  0 + mrow][sw * 8];
        b1 = *(const bf16x8*)&lds[buf][1][0][wn + 16 + mrow][sw * 8];
        if (pf1) STAGE(1, nbuf, 1, kn1 + 32);      // s3(kt+1)
        __builtin_amdgcn_s_barrier();
        LGKM0();
        __builtin_amdgcn_s_setprio(1);
#pragma unroll
        for (int t = 0; t < 8; ++t) {
            acc[t][0] = __builtin_amdgcn_mfma_f32_16x16x32_bf16(a[t], b0, acc[t][0], 0, 0, 0);
            acc[t][1] = __builtin_amdgcn_mfma_f32_16x16x32_bf16(a[t], b1, acc[t][1], 0, 0, 0);
        }
        __builtin_amdgcn_s_setprio(0);
        __builtin_amdgcn_s_barrier();

        // ---- phase 1: k-half 0, n-frags 2,3  (reads B-k0 of kt)
        b2 = *(const bf16x8*)&lds[buf][1][0][wn + 32 + mrow][sw * 8];
        b3 = *(const bf16x8*)&lds[buf][1][0][wn + 48 + mrow][sw * 8];
        if (pf2) STAGE(0, buf, 0, kn2);            // s0(kt+2)
        __builtin_amdgcn_s_barrier();
        LGKM0();
        __builtin_amdgcn_s_setprio(1);
#pragma unroll
        for (int t = 0; t < 8; ++t) {
            acc[t][2] = __builtin_amdgcn_mfma_f32_16x16x32_bf16(a[t], b2, acc[t][2], 0, 0, 0);
            acc[t][3] = __builtin_amdgcn_mfma_f32_16x16x32_bf16(a[t], b3, acc[t][3], 0, 0, 0);
        }
        __builtin_amdgcn_s_setprio(0);
        if (pf2) { VMCNT(10); } else { VMCNT(0); } // W1: s3(kt) landed
        __builtin_amdgcn_s_barrier();

        // ---- phase 2: k-half 1, n-frags 0,1  (reads A-k1, B-k1 of kt)
#pragma unroll
        for (int t = 0; t < 8; ++t)
            a[t] = *(const bf16x8*)&lds[buf][0][1][wm + t * 16 + mrow][sw * 8];
        b0 = *(const bf16x8*)&lds[buf][1][1][wn +  0 + mrow][sw * 8];
        b1 = *(const bf16x8*)&lds[buf][1][1][wn + 16 + mrow][sw * 8];
        if (pf2) STAGE(1, buf, 0, kn2);            // s1(kt+2)
        __builtin_amdgcn_s_barrier();
        LGKM0();
        __builtin_amdgcn_s_setprio(1);
#pragma unroll
        for (int t = 0; t < 8; ++t) {
            acc[t][0] = __builtin_amdgcn_mfma_f32_16x16x32_bf16(a[t], b0, acc[t][0], 0, 0, 0);
            acc[t][1] = __builtin_amdgcn_mfma_f32_16x16x32_bf16(a[t], b1, acc[t][1], 0, 0, 0);
        }
        __builtin_amdgcn_s_setprio(0);
        __builtin_amdgcn_s_barrier();

        // ---- phase 3: k-half 1, n-frags 2,3  (reads B-k1 of kt)
        b2 = *(const bf16x8*)&lds[buf][1][1][wn + 32 + mrow][sw * 8];
        b3 = *(const bf16x8*)&lds[buf][1][1][wn + 48 + mrow][sw * 8];
        if (pf2) STAGE(0, buf, 1, kn2 + 32);       // s2(kt+2)
        __builtin_amdgcn_s_barrier();
        LGKM0();
        __builtin_amdgcn_s_setprio(1);
#pragma unroll
        for (int t = 0; t < 8; ++t) {
            acc[t][2] = __builtin_amdgcn_mfma_f32_16x16x32_bf16(a[t], b2, acc[t][2], 0, 0, 0);
            acc[t][3] = __builtin_amdgcn_mfma_f32_16x16x32_bf16(a[t], b3, acc[t][3], 0, 0, 0);
        }
        __builtin_amdgcn_s_setprio(0);
        if (pf2) { VMCNT(10); } else { VMCNT(0); } // W2: s1(kt+1) landed
        __builtin_amdgcn_s_barrier();
    }

    // Epilogue: C/D layout col=lane&15, row=quad*4+reg
    const float scale = *scale_ptr;
    float* Cg = C + (size_t)(bm * 256 + wm) * N + bn * 256 + wn;
#pragma unroll
    for (int i = 0; i < 8; ++i) {
#pragma unroll
        for (int j = 0; j < 4; ++j) {
#pragma unroll
            for (int r = 0; r < 4; ++r) {
                const int row = i * 16 + quad * 4 + r;
                const int col = j * 16 + mrow;
                Cg[(size_t)row * N + col] = acc[i][j][r] * scale;
            }
        }
    }
}

// ---------------------------------------------------------------------------
// Launch
// ---------------------------------------------------------------------------
extern "C" void kernel_launch(void* const* d_in, const int* in_sizes, int n_in,
                              void* d_out, int out_size, void* d_ws, size_t ws_size,
                              hipStream_t stream) {
    const float* x   = (const float*)d_in[0];     // [4,1024,4096] fp32
    const int* pw    = (const int*)d_in[1];       // [11008*4096/4] int32
    const float* wsc = (const float*)d_in[2];     // [1] fp32

    float* out = (float*)d_out;                   // [4,1024,11008] fp32

    unsigned short* xb = (unsigned short*)d_ws;
    unsigned short* wb = (unsigned short*)((char*)d_ws + (size_t)M_DIM * IN_F * 2);

    // x convert: 16,777,216 elems / 8 per thread
    cvt_x_kernel<<<8192, 256, 0, stream>>>(x, xb);

    // unpack: 11,272,192 packed ints / 4 per thread
    unpack_w_kernel<<<11008, 256, 0, stream>>>(pw, wb);

    // GEMM: 688 tiles = 16 (M/256) x 43 (N/256), 512 threads (8 waves)
    gemm_kernel<<<688, 512, 0, stream>>>(xb, wb, out, wsc);
}